// Round 1
// baseline (5500.145 us; speedup 1.0000x reference)
//
#include <hip/hip_runtime.h>

#define N_NODES 20000
#define E_EDGES 160000
#define NFEAT   512
#define NHID    512
#define NCLASS  64
#define NLAYERS 4

// ---------------- degree / norm ----------------
__global__ __launch_bounds__(256) void deg_init(float* __restrict__ deg) {
    int i = blockIdx.x * 256 + threadIdx.x;
    if (i < N_NODES) deg[i] = 1.0f;   // self-loop contributes 1
}

__global__ __launch_bounds__(256) void deg_count(const int* __restrict__ dst,
                                                 float* __restrict__ deg) {
    int e = blockIdx.x * 256 + threadIdx.x;
    if (e < E_EDGES) atomicAdd(&deg[dst[e]], 1.0f);
}

__global__ __launch_bounds__(256) void deg_rsqrt(float* __restrict__ deg) {
    int i = blockIdx.x * 256 + threadIdx.x;
    if (i < N_NODES) deg[i] = rsqrtf(deg[i]);   // deg >= 1 always
}

// ---------------- fp32 tiled GEMM: C[M,N] = A[M,K] @ B[K,N] (+bias, +relu) ----
// 64x64 block tile, 256 threads, 4x4 micro-tile per thread, BK=16.
template <bool RELU, bool HASBIAS>
__global__ __launch_bounds__(256) void gemm_kernel(const float* __restrict__ A,
                                                   const float* __restrict__ B,
                                                   const float* __restrict__ bias,
                                                   float* __restrict__ C,
                                                   int M, int N, int K) {
    __shared__ float As[64][17];   // +1 pad breaks bank aliasing
    __shared__ float Bs[16][65];

    const int t   = threadIdx.x;
    const int bm0 = blockIdx.y * 64;
    const int bn0 = blockIdx.x * 64;
    const int tx  = t & 15;        // col group
    const int ty  = t >> 4;        // row group

    // global-load roles
    const int ar = t >> 2;          // 0..63  (A tile row)
    const int ak = (t & 3) * 4;     // 0..12  (A tile k, float4)
    const int br = t >> 4;          // 0..15  (B tile k-row)
    const int bc = (t & 15) * 4;    // 0..60  (B tile col, float4)

    float acc[4][4] = {};

    for (int kt = 0; kt < K; kt += 16) {
        float4 av = make_float4(0.f, 0.f, 0.f, 0.f);
        const int arow = bm0 + ar;
        if (arow < M) av = *(const float4*)(A + (size_t)arow * K + kt + ak);
        As[ar][ak + 0] = av.x; As[ar][ak + 1] = av.y;
        As[ar][ak + 2] = av.z; As[ar][ak + 3] = av.w;

        const float4 bv = *(const float4*)(B + (size_t)(kt + br) * N + bn0 + bc);
        Bs[br][bc + 0] = bv.x; Bs[br][bc + 1] = bv.y;
        Bs[br][bc + 2] = bv.z; Bs[br][bc + 3] = bv.w;

        __syncthreads();
#pragma unroll
        for (int k = 0; k < 16; ++k) {
            float a[4], b[4];
#pragma unroll
            for (int i = 0; i < 4; ++i) a[i] = As[ty + 16 * i][k];
#pragma unroll
            for (int j = 0; j < 4; ++j) b[j] = Bs[k][tx + 16 * j];
#pragma unroll
            for (int i = 0; i < 4; ++i)
#pragma unroll
                for (int j = 0; j < 4; ++j) acc[i][j] += a[i] * b[j];
        }
        __syncthreads();
    }

#pragma unroll
    for (int j = 0; j < 4; ++j) {
        const int col = bn0 + tx + 16 * j;
        const float bb = HASBIAS ? bias[col] : 0.0f;
#pragma unroll
        for (int i = 0; i < 4; ++i) {
            const int row = bm0 + ty + 16 * i;
            if (row < M) {
                float v = acc[i][j] + bb;
                if (RELU) v = fmaxf(v, 0.0f);
                C[(size_t)row * N + col] = v;
            }
        }
    }
}

// ---------------- edge scatter: agg[dst] += hW[src] * dinv[src]*dinv[dst] ----
// 128 threads per edge (one float4 chunk each) -> coalesced row read,
// 4 scalar atomics per thread.
__global__ __launch_bounds__(256) void scatter_edges(const float* __restrict__ hW,
                                                     const int* __restrict__ src,
                                                     const int* __restrict__ dst,
                                                     const float* __restrict__ dinv,
                                                     float* __restrict__ agg) {
    const long long idx = (long long)blockIdx.x * 256 + threadIdx.x;
    const int e = (int)(idx >> 7);    // /128
    const int c = (int)(idx & 127);
    if (e >= E_EDGES) return;
    const int s = src[e];
    const int d = dst[e];
    const float nrm = dinv[s] * dinv[d];
    const float4 v = *(const float4*)(hW + (size_t)s * NHID + c * 4);
    float* o = agg + (size_t)d * NHID + c * 4;
    atomicAdd(o + 0, v.x * nrm);
    atomicAdd(o + 1, v.y * nrm);
    atomicAdd(o + 2, v.z * nrm);
    atomicAdd(o + 3, v.w * nrm);
}

// ---------------- epilogue: h = relu(agg + hW * dinv^2 + bias) ----------------
__global__ __launch_bounds__(256) void finish_layer(float* __restrict__ agg,
                                                    const float* __restrict__ hW,
                                                    const float* __restrict__ dinv,
                                                    const float* __restrict__ bias) {
    const long long idx = (long long)blockIdx.x * 256 + threadIdx.x;
    if (idx >= (long long)N_NODES * (NHID / 4)) return;
    const int i = (int)(idx >> 7);
    const int c = (int)(idx & 127);
    const float di = dinv[i];
    const float sl = di * di;            // self-loop norm
    const size_t off = (size_t)i * NHID + c * 4;
    const float4 a  = *(const float4*)(agg + off);
    const float4 hv = *(const float4*)(hW + off);
    float4 r;
    r.x = fmaxf(a.x + hv.x * sl + bias[c * 4 + 0], 0.0f);
    r.y = fmaxf(a.y + hv.y * sl + bias[c * 4 + 1], 0.0f);
    r.z = fmaxf(a.z + hv.z * sl + bias[c * 4 + 2], 0.0f);
    r.w = fmaxf(a.w + hv.w * sl + bias[c * 4 + 3], 0.0f);
    *(float4*)(agg + off) = r;
}

extern "C" void kernel_launch(void* const* d_in, const int* in_sizes, int n_in,
                              void* d_out, int out_size, void* d_ws, size_t ws_size,
                              hipStream_t stream) {
    const float* x       = (const float*)d_in[0];
    const int*   ei      = (const int*)d_in[1];
    const float* W_enc   = (const float*)d_in[2];
    const float* b_enc   = (const float*)d_in[3];
    const float* W_convs = (const float*)d_in[4];
    const float* b_convs = (const float*)d_in[5];
    const float* W_dec   = (const float*)d_in[6];
    const float* b_dec   = (const float*)d_in[7];
    float* out = (float*)d_out;

    const int* src = ei;            // edge_index[0]
    const int* dst = ei + E_EDGES;  // edge_index[1]

    char* ws = (char*)d_ws;
    float* dinv = (float*)ws;                                   // N floats
    float* B1 = (float*)(ws + ((size_t)N_NODES * 4 + 255) / 256 * 256);
    float* B2 = B1 + (size_t)N_NODES * NHID;                    // 41 MB each

    // degrees -> dinv (in place)
    deg_init<<<(N_NODES + 255) / 256, 256, 0, stream>>>(dinv);
    deg_count<<<(E_EDGES + 255) / 256, 256, 0, stream>>>(dst, dinv);
    deg_rsqrt<<<(N_NODES + 255) / 256, 256, 0, stream>>>(dinv);

    // encoder: B1 = relu(x @ W_enc + b_enc)
    dim3 g512((NHID + 63) / 64, (N_NODES + 63) / 64);
    gemm_kernel<true, true><<<g512, 256, 0, stream>>>(x, W_enc, b_enc, B1,
                                                      N_NODES, NHID, NFEAT);

    for (int L = 0; L < NLAYERS; ++L) {
        // B2 = B1 @ W_convs[L]
        gemm_kernel<false, false><<<g512, 256, 0, stream>>>(
            B1, W_convs + (size_t)L * NHID * NHID, nullptr, B2,
            N_NODES, NHID, NHID);
        // B1 (old h no longer needed) becomes agg
        hipMemsetAsync(B1, 0, (size_t)N_NODES * NHID * sizeof(float), stream);
        scatter_edges<<<(int)(((long long)E_EDGES * 128 + 255) / 256), 256, 0, stream>>>(
            B2, src, dst, dinv, B1);
        finish_layer<<<(int)(((long long)N_NODES * 128 + 255) / 256), 256, 0, stream>>>(
            B1, B2, dinv, b_convs + (size_t)L * NHID);
    }

    // decoder: out = B1 @ W_dec + b_dec
    dim3 gdec((NCLASS + 63) / 64, (N_NODES + 63) / 64);
    gemm_kernel<false, true><<<gdec, 256, 0, stream>>>(B1, W_dec, b_dec, out,
                                                       N_NODES, NCLASS, NHID);
}

// Round 2
// 1318.161 us; speedup vs baseline: 4.1726x; 4.1726x over previous
//
#include <hip/hip_runtime.h>

#define N_NODES 20000
#define E_EDGES 160000
#define NFEAT   512
#define NHID    512
#define NCLASS  64
#define NLAYERS 4

// ================= CSR build =================

// count in-degree (int atomics, E=160K -> cheap)
__global__ __launch_bounds__(256) void csr_count(const int* __restrict__ dst,
                                                 int* __restrict__ counts) {
    int e = blockIdx.x * 256 + threadIdx.x;
    if (e < E_EDGES) atomicAdd(&counts[dst[e]], 1);
}

// single-block exclusive scan over counts -> row_ptr[N+1]
__global__ __launch_bounds__(256) void scan_rowptr(const int* __restrict__ counts,
                                                   int* __restrict__ row_ptr) {
    __shared__ int part[256];
    const int t = threadIdx.x;
    const int CH = (N_NODES + 255) / 256;   // 79
    const int base = t * CH;
    int sum = 0;
    for (int i = 0; i < CH; ++i) {
        int idx = base + i;
        if (idx < N_NODES) sum += counts[idx];
    }
    part[t] = sum;
    __syncthreads();
    // Hillis-Steele inclusive scan
    for (int off = 1; off < 256; off <<= 1) {
        int v = (t >= off) ? part[t - off] : 0;
        __syncthreads();
        part[t] += v;
        __syncthreads();
    }
    int run = (t == 0) ? 0 : part[t - 1];
    for (int i = 0; i < CH; ++i) {
        int idx = base + i;
        if (idx < N_NODES) {
            row_ptr[idx] = run;
            run += counts[idx];
        }
    }
    if (t == 255) row_ptr[N_NODES] = run;
}

// dinv[i] = rsqrt(indeg+1) ; cursor[i] = row_ptr[i]
__global__ __launch_bounds__(256) void node_prep(const int* __restrict__ counts,
                                                 const int* __restrict__ row_ptr,
                                                 float* __restrict__ dinv,
                                                 int* __restrict__ cursor) {
    int i = blockIdx.x * 256 + threadIdx.x;
    if (i < N_NODES) {
        dinv[i] = rsqrtf((float)counts[i] + 1.0f);   // +1 self-loop
        cursor[i] = row_ptr[i];
    }
}

// fill col + weight (dinv[s]*dinv[d]) per edge
__global__ __launch_bounds__(256) void csr_fill(const int* __restrict__ src,
                                                const int* __restrict__ dst,
                                                const float* __restrict__ dinv,
                                                int* __restrict__ cursor,
                                                int* __restrict__ col,
                                                float* __restrict__ wgt) {
    int e = blockIdx.x * 256 + threadIdx.x;
    if (e < E_EDGES) {
        int s = src[e], d = dst[e];
        int pos = atomicAdd(&cursor[d], 1);
        col[pos] = s;
        wgt[pos] = dinv[s] * dinv[d];
    }
}

// ================= fp32 tiled GEMM (unchanged from R1) =================
template <bool RELU, bool HASBIAS>
__global__ __launch_bounds__(256) void gemm_kernel(const float* __restrict__ A,
                                                   const float* __restrict__ B,
                                                   const float* __restrict__ bias,
                                                   float* __restrict__ C,
                                                   int M, int N, int K) {
    __shared__ float As[64][17];
    __shared__ float Bs[16][65];

    const int t   = threadIdx.x;
    const int bm0 = blockIdx.y * 64;
    const int bn0 = blockIdx.x * 64;
    const int tx  = t & 15;
    const int ty  = t >> 4;

    const int ar = t >> 2;
    const int ak = (t & 3) * 4;
    const int br = t >> 4;
    const int bc = (t & 15) * 4;

    float acc[4][4] = {};

    for (int kt = 0; kt < K; kt += 16) {
        float4 av = make_float4(0.f, 0.f, 0.f, 0.f);
        const int arow = bm0 + ar;
        if (arow < M) av = *(const float4*)(A + (size_t)arow * K + kt + ak);
        As[ar][ak + 0] = av.x; As[ar][ak + 1] = av.y;
        As[ar][ak + 2] = av.z; As[ar][ak + 3] = av.w;

        const float4 bv = *(const float4*)(B + (size_t)(kt + br) * N + bn0 + bc);
        Bs[br][bc + 0] = bv.x; Bs[br][bc + 1] = bv.y;
        Bs[br][bc + 2] = bv.z; Bs[br][bc + 3] = bv.w;

        __syncthreads();
#pragma unroll
        for (int k = 0; k < 16; ++k) {
            float a[4], b[4];
#pragma unroll
            for (int i = 0; i < 4; ++i) a[i] = As[ty + 16 * i][k];
#pragma unroll
            for (int j = 0; j < 4; ++j) b[j] = Bs[k][tx + 16 * j];
#pragma unroll
            for (int i = 0; i < 4; ++i)
#pragma unroll
                for (int j = 0; j < 4; ++j) acc[i][j] += a[i] * b[j];
        }
        __syncthreads();
    }

#pragma unroll
    for (int j = 0; j < 4; ++j) {
        const int col = bn0 + tx + 16 * j;
        const float bb = HASBIAS ? bias[col] : 0.0f;
#pragma unroll
        for (int i = 0; i < 4; ++i) {
            const int row = bm0 + ty + 16 * i;
            if (row < M) {
                float v = acc[i][j] + bb;
                if (RELU) v = fmaxf(v, 0.0f);
                C[(size_t)row * N + col] = v;
            }
        }
    }
}

// ================= CSR-pull aggregation, fused epilogue =================
// one block (128 threads = 2 waves) per destination node; thread t owns
// features [4t, 4t+4). out = relu(sum_nbr w*hW[s] + dinv^2*hW[d] + bias)
__global__ __launch_bounds__(128) void gcn_aggregate(const float* __restrict__ hW,
                                                     const int* __restrict__ row_ptr,
                                                     const int* __restrict__ col,
                                                     const float* __restrict__ wgt,
                                                     const float* __restrict__ dinv,
                                                     const float* __restrict__ bias,
                                                     float* __restrict__ out) {
    const int d = blockIdx.x;
    const int t = threadIdx.x;           // 0..127
    const int beg = row_ptr[d];
    const int end = row_ptr[d + 1];
    const size_t foff = (size_t)t * 4;

    const float di = dinv[d];
    const float sl = di * di;
    const float4 self = *(const float4*)(hW + (size_t)d * NHID + foff);
    float4 acc;
    acc.x = self.x * sl; acc.y = self.y * sl;
    acc.z = self.z * sl; acc.w = self.w * sl;

    for (int j = beg; j < end; ++j) {
        const int s   = col[j];
        const float w = wgt[j];
        const float4 v = *(const float4*)(hW + (size_t)s * NHID + foff);
        acc.x += v.x * w; acc.y += v.y * w;
        acc.z += v.z * w; acc.w += v.w * w;
    }

    const float4 b = *(const float4*)(bias + foff);
    float4 r;
    r.x = fmaxf(acc.x + b.x, 0.0f);
    r.y = fmaxf(acc.y + b.y, 0.0f);
    r.z = fmaxf(acc.z + b.z, 0.0f);
    r.w = fmaxf(acc.w + b.w, 0.0f);
    *(float4*)(out + (size_t)d * NHID + foff) = r;
}

// ================= launch =================
extern "C" void kernel_launch(void* const* d_in, const int* in_sizes, int n_in,
                              void* d_out, int out_size, void* d_ws, size_t ws_size,
                              hipStream_t stream) {
    const float* x       = (const float*)d_in[0];
    const int*   ei      = (const int*)d_in[1];
    const float* W_enc   = (const float*)d_in[2];
    const float* b_enc   = (const float*)d_in[3];
    const float* W_convs = (const float*)d_in[4];
    const float* b_convs = (const float*)d_in[5];
    const float* W_dec   = (const float*)d_in[6];
    const float* b_dec   = (const float*)d_in[7];
    float* out = (float*)d_out;

    const int* src = ei;            // edge_index[0]
    const int* dst = ei + E_EDGES;  // edge_index[1]

    // workspace layout (all 256B-aligned)
    char* ws = (char*)d_ws;
    auto alloc = [&](size_t bytes) {
        char* p = ws;
        ws += (bytes + 255) / 256 * 256;
        return p;
    };
    float* dinv    = (float*)alloc(N_NODES * 4);
    int*   counts  = (int*)  alloc(N_NODES * 4);
    int*   row_ptr = (int*)  alloc((N_NODES + 1) * 4);
    int*   cursor  = (int*)  alloc(N_NODES * 4);
    int*   colA    = (int*)  alloc(E_EDGES * 4);
    float* wgtA    = (float*)alloc(E_EDGES * 4);
    float* B1      = (float*)alloc((size_t)N_NODES * NHID * 4);
    float* B2      = (float*)alloc((size_t)N_NODES * NHID * 4);

    // ---- CSR build ----
    hipMemsetAsync(counts, 0, N_NODES * sizeof(int), stream);
    csr_count<<<(E_EDGES + 255) / 256, 256, 0, stream>>>(dst, counts);
    scan_rowptr<<<1, 256, 0, stream>>>(counts, row_ptr);
    node_prep<<<(N_NODES + 255) / 256, 256, 0, stream>>>(counts, row_ptr, dinv, cursor);
    csr_fill<<<(E_EDGES + 255) / 256, 256, 0, stream>>>(src, dst, dinv, cursor, colA, wgtA);

    // ---- encoder ----
    dim3 g512((NHID + 63) / 64, (N_NODES + 63) / 64);
    gemm_kernel<true, true><<<g512, 256, 0, stream>>>(x, W_enc, b_enc, B1,
                                                      N_NODES, NHID, NFEAT);

    // ---- conv layers ----
    for (int L = 0; L < NLAYERS; ++L) {
        gemm_kernel<false, false><<<g512, 256, 0, stream>>>(
            B1, W_convs + (size_t)L * NHID * NHID, nullptr, B2,
            N_NODES, NHID, NHID);
        gcn_aggregate<<<N_NODES, 128, 0, stream>>>(
            B2, row_ptr, colA, wgtA, dinv, b_convs + (size_t)L * NHID, B1);
    }

    // ---- decoder ----
    dim3 gdec((NCLASS + 63) / 64, (N_NODES + 63) / 64);
    gemm_kernel<false, true><<<gdec, 256, 0, stream>>>(B1, W_dec, b_dec, out,
                                                       N_NODES, NCLASS, NHID);
}

// Round 3
// 429.484 us; speedup vs baseline: 12.8064x; 3.0692x over previous
//
#include <hip/hip_runtime.h>

#define N_NODES 20000
#define E_EDGES 160000
#define NFEAT   512
#define NHID    512
#define NCLASS  64
#define NLAYERS 4

using bf16x8 = __attribute__((ext_vector_type(8))) short;   // 4 VGPRs (MFMA A/B frag)
using f32x4  = __attribute__((ext_vector_type(4))) float;   // MFMA C/D frag

__device__ __forceinline__ unsigned short f2bf(float f) {
    union { float f; unsigned int u; } v; v.f = f;
    unsigned int u = v.u + 0x7FFFu + ((v.u >> 16) & 1u);   // RNE
    return (unsigned short)(u >> 16);
}
__device__ __forceinline__ float bf2f(unsigned short h) {
    union { unsigned int u; float f; } v; v.u = ((unsigned int)h) << 16;
    return v.f;
}
__device__ __forceinline__ void gl2lds16(const void* gptr, void* lptr) {
    __builtin_amdgcn_global_load_lds(
        (const __attribute__((address_space(1))) unsigned int*)gptr,
        (__attribute__((address_space(3))) unsigned int*)lptr,
        16, 0, 0);
}

// ================= preprocessing =================

// fp32 -> bf16, float4 granularity
__global__ __launch_bounds__(256) void conv_f32_bf16(const float* __restrict__ in,
                                                     unsigned short* __restrict__ out,
                                                     int n4) {
    int i = blockIdx.x * 256 + threadIdx.x;
    if (i < n4) {
        float4 v = ((const float4*)in)[i];
        ushort4 o;
        o.x = f2bf(v.x); o.y = f2bf(v.y); o.z = f2bf(v.z); o.w = f2bf(v.w);
        ((ushort4*)out)[i] = o;
    }
}

// W[K][N] fp32 -> WT[N][K] bf16 (32x32 LDS tiles; K,N multiples of 32)
__global__ __launch_bounds__(256) void transpose_bf16(const float* __restrict__ W,
                                                      unsigned short* __restrict__ WT,
                                                      int K, int N) {
    __shared__ float tile[32][33];
    const int k0 = blockIdx.y * 32, n0 = blockIdx.x * 32;
    const int tx = threadIdx.x & 31, ty = threadIdx.x >> 5;   // 32 x 8
#pragma unroll
    for (int i = 0; i < 32; i += 8)
        tile[ty + i][tx] = W[(size_t)(k0 + ty + i) * N + n0 + tx];
    __syncthreads();
#pragma unroll
    for (int i = 0; i < 32; i += 8)
        WT[(size_t)(n0 + ty + i) * K + k0 + tx] = f2bf(tile[tx][ty + i]);
}

// ================= CSR build =================
__global__ __launch_bounds__(256) void csr_count(const int* __restrict__ dst,
                                                 int* __restrict__ counts) {
    int e = blockIdx.x * 256 + threadIdx.x;
    if (e < E_EDGES) atomicAdd(&counts[dst[e]], 1);
}

__global__ __launch_bounds__(256) void scan_rowptr(const int* __restrict__ counts,
                                                   int* __restrict__ row_ptr) {
    __shared__ int part[256];
    const int t = threadIdx.x;
    const int CH = (N_NODES + 255) / 256;
    const int base = t * CH;
    int sum = 0;
    for (int i = 0; i < CH; ++i) {
        int idx = base + i;
        if (idx < N_NODES) sum += counts[idx];
    }
    part[t] = sum;
    __syncthreads();
    for (int off = 1; off < 256; off <<= 1) {
        int v = (t >= off) ? part[t - off] : 0;
        __syncthreads();
        part[t] += v;
        __syncthreads();
    }
    int run = (t == 0) ? 0 : part[t - 1];
    for (int i = 0; i < CH; ++i) {
        int idx = base + i;
        if (idx < N_NODES) {
            row_ptr[idx] = run;
            run += counts[idx];
        }
    }
    if (t == 255) row_ptr[N_NODES] = run;
}

__global__ __launch_bounds__(256) void node_prep(const int* __restrict__ counts,
                                                 const int* __restrict__ row_ptr,
                                                 float* __restrict__ dinv,
                                                 int* __restrict__ cursor) {
    int i = blockIdx.x * 256 + threadIdx.x;
    if (i < N_NODES) {
        dinv[i] = rsqrtf((float)counts[i] + 1.0f);
        cursor[i] = row_ptr[i];
    }
}

__global__ __launch_bounds__(256) void csr_fill(const int* __restrict__ src,
                                                const int* __restrict__ dst,
                                                const float* __restrict__ dinv,
                                                int* __restrict__ cursor,
                                                int* __restrict__ col,
                                                float* __restrict__ wgt) {
    int e = blockIdx.x * 256 + threadIdx.x;
    if (e < E_EDGES) {
        int s = src[e], d = dst[e];
        int pos = atomicAdd(&cursor[d], 1);
        col[pos] = s;
        wgt[pos] = dinv[s] * dinv[d];
    }
}

// ================= bf16 MFMA GEMM =================
// C[M,N] = A[M,K] @ B[K,N]; A bf16 row-major, BT = B^T bf16 [N][K] row-major.
// BM=128, BK=32, BN in {128,64}. 256 threads = 4 waves.
template <int BN, bool RELU, bool HASBIAS, bool OUTBF16>
__global__ __launch_bounds__(256) void gemm_mfma(const unsigned short* __restrict__ A,
                                                 const unsigned short* __restrict__ BT,
                                                 const float* __restrict__ bias,
                                                 void* __restrict__ Cout,
                                                 int M, int N, int K) {
    constexpr int BM = 128, BK = 32;
    constexpr int R = (BN == 128) ? 4 : 2;      // 16-row blocks per wave
    constexpr int C = 4;                        // 16-col blocks per wave
    __shared__ unsigned short lA[BM * BK];      // [m][k], 8 KB
    __shared__ unsigned short lB[BN * BK];      // [n][k]

    const int t    = threadIdx.x;
    const int lane = t & 63;
    const int wv   = t >> 6;
    const int wr   = (BN == 128) ? (wv >> 1) : wv;
    const int wc   = (BN == 128) ? (wv & 1) : 0;
    const int lm   = lane & 15;
    const int quad = lane >> 4;

    const int m0 = blockIdx.y * BM;
    const int n0 = blockIdx.x * BN;

    f32x4 acc[R][C] = {};

    for (int kt = 0; kt < K; kt += BK) {
        // ---- stage A tile (2 rounds of 256 lanes x 16B) ----
#pragma unroll
        for (int i = 0; i < (BM * BK) / (256 * 8); ++i) {
            int idx = i * 256 + t;
            int row = idx >> 2;              // BK/8 = 4 chunks per row
            int kof = (idx & 3) << 3;
            int gr = m0 + row; if (gr >= M) gr = M - 1;   // clamp (dup data, masked at store)
            gl2lds16(A + (size_t)gr * K + kt + kof, &lA[idx * 8]);
        }
        // ---- stage B^T tile ----
#pragma unroll
        for (int i = 0; i < (BN * BK) / (256 * 8); ++i) {
            int idx = i * 256 + t;
            int row = idx >> 2;
            int kof = (idx & 3) << 3;
            gl2lds16(BT + (size_t)(n0 + row) * K + kt + kof, &lB[idx * 8]);
        }
        __syncthreads();

        bf16x8 af[R], bfr[C];
#pragma unroll
        for (int r = 0; r < R; ++r)
            af[r] = *(const bf16x8*)&lA[(wr * R * 16 + r * 16 + lm) * BK + quad * 8];
#pragma unroll
        for (int c = 0; c < C; ++c)
            bfr[c] = *(const bf16x8*)&lB[(wc * C * 16 + c * 16 + lm) * BK + quad * 8];
#pragma unroll
        for (int r = 0; r < R; ++r)
#pragma unroll
            for (int c = 0; c < C; ++c)
                acc[r][c] = __builtin_amdgcn_mfma_f32_16x16x32_bf16(af[r], bfr[c],
                                                                    acc[r][c], 0, 0, 0);
        __syncthreads();
    }

    // ---- epilogue: C/D layout col=lane&15, row=quad*4+reg ----
#pragma unroll
    for (int r = 0; r < R; ++r) {
#pragma unroll
        for (int c = 0; c < C; ++c) {
            const int colg = n0 + wc * C * 16 + c * 16 + lm;
            const float bb = HASBIAS ? bias[colg] : 0.0f;
            const int rowb = m0 + wr * R * 16 + r * 16 + quad * 4;
#pragma unroll
            for (int i = 0; i < 4; ++i) {
                const int rr = rowb + i;
                if (rr < M) {
                    float v = acc[r][c][i] + bb;
                    if (RELU) v = fmaxf(v, 0.0f);
                    if (OUTBF16)
                        ((unsigned short*)Cout)[(size_t)rr * N + colg] = f2bf(v);
                    else
                        ((float*)Cout)[(size_t)rr * N + colg] = v;
                }
            }
        }
    }
}

// ================= CSR-pull aggregation (bf16 in/out, fp32 accum) =================
__global__ __launch_bounds__(128) void gcn_aggregate(const unsigned short* __restrict__ hW,
                                                     const int* __restrict__ row_ptr,
                                                     const int* __restrict__ col,
                                                     const float* __restrict__ wgt,
                                                     const float* __restrict__ dinv,
                                                     const float* __restrict__ bias,
                                                     unsigned short* __restrict__ out) {
    const int d = blockIdx.x;
    const int t = threadIdx.x;               // 0..127, owns features 4t..4t+3
    const int beg = row_ptr[d];
    const int end = row_ptr[d + 1];
    const size_t foff = (size_t)t * 4;

    const float di = dinv[d];
    const float sl = di * di;
    ushort4 sv = *(const ushort4*)(hW + (size_t)d * NHID + foff);
    float ax = bf2f(sv.x) * sl, ay = bf2f(sv.y) * sl,
          az = bf2f(sv.z) * sl, aw = bf2f(sv.w) * sl;

    for (int j = beg; j < end; ++j) {
        const int s   = col[j];
        const float w = wgt[j];
        ushort4 v = *(const ushort4*)(hW + (size_t)s * NHID + foff);
        ax += bf2f(v.x) * w; ay += bf2f(v.y) * w;
        az += bf2f(v.z) * w; aw += bf2f(v.w) * w;
    }

    const float4 b = *(const float4*)(bias + foff);
    ushort4 r;
    r.x = f2bf(fmaxf(ax + b.x, 0.0f));
    r.y = f2bf(fmaxf(ay + b.y, 0.0f));
    r.z = f2bf(fmaxf(az + b.z, 0.0f));
    r.w = f2bf(fmaxf(aw + b.w, 0.0f));
    *(ushort4*)(out + (size_t)d * NHID + foff) = r;
}

// ================= launch =================
extern "C" void kernel_launch(void* const* d_in, const int* in_sizes, int n_in,
                              void* d_out, int out_size, void* d_ws, size_t ws_size,
                              hipStream_t stream) {
    const float* x       = (const float*)d_in[0];
    const int*   ei      = (const int*)d_in[1];
    const float* W_enc   = (const float*)d_in[2];
    const float* b_enc   = (const float*)d_in[3];
    const float* W_convs = (const float*)d_in[4];
    const float* b_convs = (const float*)d_in[5];
    const float* W_dec   = (const float*)d_in[6];
    const float* b_dec   = (const float*)d_in[7];
    float* out = (float*)d_out;

    const int* src = ei;
    const int* dst = ei + E_EDGES;

    char* ws = (char*)d_ws;
    auto alloc = [&](size_t bytes) {
        char* p = ws;
        ws += (bytes + 255) / 256 * 256;
        return p;
    };
    float* dinv     = (float*)alloc(N_NODES * 4);
    int*   counts   = (int*)  alloc(N_NODES * 4);
    int*   row_ptr  = (int*)  alloc((N_NODES + 1) * 4);
    int*   cursor   = (int*)  alloc(N_NODES * 4);
    int*   colA     = (int*)  alloc(E_EDGES * 4);
    float* wgtA     = (float*)alloc(E_EDGES * 4);
    unsigned short* xbf   = (unsigned short*)alloc((size_t)N_NODES * NFEAT * 2);
    unsigned short* WencT = (unsigned short*)alloc((size_t)NFEAT * NHID * 2);
    unsigned short* WcvT  = (unsigned short*)alloc((size_t)NLAYERS * NHID * NHID * 2);
    unsigned short* WdecT = (unsigned short*)alloc((size_t)NHID * NCLASS * 2);
    unsigned short* B1    = (unsigned short*)alloc((size_t)N_NODES * NHID * 2);
    unsigned short* B2    = (unsigned short*)alloc((size_t)N_NODES * NHID * 2);

    // ---- CSR build ----
    hipMemsetAsync(counts, 0, N_NODES * sizeof(int), stream);
    csr_count<<<(E_EDGES + 255) / 256, 256, 0, stream>>>(dst, counts);
    scan_rowptr<<<1, 256, 0, stream>>>(counts, row_ptr);
    node_prep<<<(N_NODES + 255) / 256, 256, 0, stream>>>(counts, row_ptr, dinv, cursor);
    csr_fill<<<(E_EDGES + 255) / 256, 256, 0, stream>>>(src, dst, dinv, cursor, colA, wgtA);

    // ---- convert inputs to bf16 ----
    {
        int n4 = N_NODES * NFEAT / 4;
        conv_f32_bf16<<<(n4 + 255) / 256, 256, 0, stream>>>(x, xbf, n4);
    }
    transpose_bf16<<<dim3(NHID / 32, NFEAT / 32), 256, 0, stream>>>(W_enc, WencT, NFEAT, NHID);
    for (int L = 0; L < NLAYERS; ++L)
        transpose_bf16<<<dim3(NHID / 32, NHID / 32), 256, 0, stream>>>(
            W_convs + (size_t)L * NHID * NHID, WcvT + (size_t)L * NHID * NHID, NHID, NHID);
    transpose_bf16<<<dim3(NCLASS / 32, NHID / 32), 256, 0, stream>>>(W_dec, WdecT, NHID, NCLASS);

    const int MB = (N_NODES + 127) / 128;   // 157

    // ---- encoder: B1 = relu(x @ W_enc + b_enc), bf16 out ----
    gemm_mfma<128, true, true, true><<<dim3(NHID / 128, MB), 256, 0, stream>>>(
        xbf, WencT, b_enc, B1, N_NODES, NHID, NFEAT);

    // ---- conv layers ----
    for (int L = 0; L < NLAYERS; ++L) {
        gemm_mfma<128, false, false, true><<<dim3(NHID / 128, MB), 256, 0, stream>>>(
            B1, WcvT + (size_t)L * NHID * NHID, nullptr, B2, N_NODES, NHID, NHID);
        gcn_aggregate<<<N_NODES, 128, 0, stream>>>(
            B2, row_ptr, colA, wgtA, dinv, b_convs + (size_t)L * NHID, B1);
    }

    // ---- decoder: out = B1 @ W_dec + b_dec, fp32 out ----
    gemm_mfma<64, false, true, false><<<dim3(NCLASS / 64, MB), 256, 0, stream>>>(
        B1, WdecT, b_dec, out, N_NODES, NCLASS, NHID);
}

// Round 4
// 399.939 us; speedup vs baseline: 13.7525x; 1.0739x over previous
//
#include <hip/hip_runtime.h>

#define N_NODES 20000
#define E_EDGES 160000
#define NFEAT   512
#define NHID    512
#define NCLASS  64
#define NLAYERS 4

#define SCAN_CHUNK 1024
#define NBLK ((N_NODES + SCAN_CHUNK - 1) / SCAN_CHUNK)   // 20

using bf16x8 = __attribute__((ext_vector_type(8))) short;          // MFMA A/B frag
using f32x4  = __attribute__((ext_vector_type(4))) float;          // MFMA C/D frag
using u16x8  = __attribute__((ext_vector_type(8))) unsigned short; // 16B bf16 vector

__device__ __forceinline__ unsigned short f2bf(float f) {
    union { float f; unsigned int u; } v; v.f = f;
    unsigned int u = v.u + 0x7FFFu + ((v.u >> 16) & 1u);   // RNE
    return (unsigned short)(u >> 16);
}
__device__ __forceinline__ float bf2f(unsigned short h) {
    union { unsigned int u; float f; } v; v.u = ((unsigned int)h) << 16;
    return v.f;
}
__device__ __forceinline__ void gl2lds16(const void* gptr, void* lptr) {
    __builtin_amdgcn_global_load_lds(
        (const __attribute__((address_space(1))) unsigned int*)gptr,
        (__attribute__((address_space(3))) unsigned int*)lptr,
        16, 0, 0);
}

// ================= preprocessing =================

__global__ __launch_bounds__(256) void conv_f32_bf16(const float* __restrict__ in,
                                                     unsigned short* __restrict__ out,
                                                     int n4) {
    int i = blockIdx.x * 256 + threadIdx.x;
    if (i < n4) {
        float4 v = ((const float4*)in)[i];
        ushort4 o;
        o.x = f2bf(v.x); o.y = f2bf(v.y); o.z = f2bf(v.z); o.w = f2bf(v.w);
        ((ushort4*)out)[i] = o;
    }
}

// W[K][N] fp32 -> WT[N][K] bf16
__global__ __launch_bounds__(256) void transpose_bf16(const float* __restrict__ W,
                                                      unsigned short* __restrict__ WT,
                                                      int K, int N) {
    __shared__ float tile[32][33];
    const int k0 = blockIdx.y * 32, n0 = blockIdx.x * 32;
    const int tx = threadIdx.x & 31, ty = threadIdx.x >> 5;
#pragma unroll
    for (int i = 0; i < 32; i += 8)
        tile[ty + i][tx] = W[(size_t)(k0 + ty + i) * N + n0 + tx];
    __syncthreads();
#pragma unroll
    for (int i = 0; i < 32; i += 8)
        WT[(size_t)(n0 + ty + i) * K + k0 + tx] = f2bf(tile[tx][ty + i]);
}

// ================= CSR build =================
__global__ __launch_bounds__(256) void csr_count(const int* __restrict__ dst,
                                                 int* __restrict__ counts) {
    int e = blockIdx.x * 256 + threadIdx.x;
    if (e < E_EDGES) atomicAdd(&counts[dst[e]], 1);
}

// phase 1: per-block (1024-count) sums, coalesced int4
__global__ __launch_bounds__(256) void block_sums(const int* __restrict__ counts,
                                                  int* __restrict__ bsums) {
    __shared__ int red[256];
    const int b = blockIdx.x, t = threadIdx.x;
    const int base = b * SCAN_CHUNK + t * 4;
    int s = 0;
    if (base + 3 < N_NODES) {
        int4 v = *(const int4*)(counts + base);
        s = v.x + v.y + v.z + v.w;
    } else {
        for (int i = 0; i < 4; ++i)
            if (base + i < N_NODES) s += counts[base + i];
    }
    red[t] = s;
    __syncthreads();
    for (int off = 128; off > 0; off >>= 1) {
        if (t < off) red[t] += red[t + off];
        __syncthreads();
    }
    if (t == 0) bsums[b] = red[0];
}

// phase 2: 1-wave exclusive scan of NBLK block sums
__global__ __launch_bounds__(64) void scan_bsums(const int* __restrict__ bsums,
                                                 int* __restrict__ boffs) {
    const int t = threadIdx.x;
    const int orig = (t < NBLK) ? bsums[t] : 0;
    int v = orig;
    for (int off = 1; off < 64; off <<= 1) {
        int u = __shfl_up(v, off, 64);
        if (t >= off) v += u;
    }
    if (t < NBLK) boffs[t] = v - orig;   // exclusive
}

// phase 3: per-block scatter of row_ptr
__global__ __launch_bounds__(256) void write_rowptr(const int* __restrict__ counts,
                                                    const int* __restrict__ boffs,
                                                    int* __restrict__ row_ptr) {
    __shared__ int part[256];
    const int b = blockIdx.x, t = threadIdx.x;
    const int base = b * SCAN_CHUNK + t * 4;
    int c[4], s = 0;
    for (int i = 0; i < 4; ++i) {
        int idx = base + i;
        c[i] = (idx < N_NODES) ? counts[idx] : 0;
        s += c[i];
    }
    part[t] = s;
    __syncthreads();
    for (int off = 1; off < 256; off <<= 1) {
        int v = (t >= off) ? part[t - off] : 0;
        __syncthreads();
        part[t] += v;
        __syncthreads();
    }
    int run = boffs[b] + ((t == 0) ? 0 : part[t - 1]);
    for (int i = 0; i < 4; ++i) {
        int idx = base + i;
        if (idx < N_NODES) { row_ptr[idx] = run; run += c[i]; }
    }
    if (b == 0 && t == 0) row_ptr[N_NODES] = E_EDGES;   // total is compile-time known
}

__global__ __launch_bounds__(256) void node_prep(const int* __restrict__ counts,
                                                 const int* __restrict__ row_ptr,
                                                 float* __restrict__ dinv,
                                                 int* __restrict__ cursor) {
    int i = blockIdx.x * 256 + threadIdx.x;
    if (i < N_NODES) {
        dinv[i] = rsqrtf((float)counts[i] + 1.0f);
        cursor[i] = row_ptr[i];
    }
}

__global__ __launch_bounds__(256) void csr_fill(const int* __restrict__ src,
                                                const int* __restrict__ dst,
                                                const float* __restrict__ dinv,
                                                int* __restrict__ cursor,
                                                int* __restrict__ col,
                                                float* __restrict__ wgt) {
    int e = blockIdx.x * 256 + threadIdx.x;
    if (e < E_EDGES) {
        int s = src[e], d = dst[e];
        int pos = atomicAdd(&cursor[d], 1);
        col[pos] = s;
        wgt[pos] = dinv[s] * dinv[d];
    }
}

// ================= bf16 MFMA GEMM =================
// C[M,N] = A[M,K] @ B[K,N]; A bf16 row-major, BT = B^T bf16 [N][K] row-major.
template <int BN, bool RELU, bool HASBIAS, bool OUTBF16>
__global__ __launch_bounds__(256) void gemm_mfma(const unsigned short* __restrict__ A,
                                                 const unsigned short* __restrict__ BT,
                                                 const float* __restrict__ bias,
                                                 void* __restrict__ Cout,
                                                 int M, int N, int K) {
    constexpr int BM = 128, BK = 32;
    constexpr int R = (BN == 128) ? 4 : 2;
    constexpr int C = 4;
    __shared__ unsigned short lA[BM * BK];
    __shared__ unsigned short lB[BN * BK];

    const int t    = threadIdx.x;
    const int lane = t & 63;
    const int wv   = t >> 6;
    const int wr   = (BN == 128) ? (wv >> 1) : wv;
    const int wc   = (BN == 128) ? (wv & 1) : 0;
    const int lm   = lane & 15;
    const int quad = lane >> 4;

    const int m0 = blockIdx.y * BM;
    const int n0 = blockIdx.x * BN;

    f32x4 acc[R][C] = {};

    for (int kt = 0; kt < K; kt += BK) {
#pragma unroll
        for (int i = 0; i < (BM * BK) / (256 * 8); ++i) {
            int idx = i * 256 + t;
            int row = idx >> 2;
            int kof = (idx & 3) << 3;
            int gr = m0 + row; if (gr >= M) gr = M - 1;
            gl2lds16(A + (size_t)gr * K + kt + kof, &lA[idx * 8]);
        }
#pragma unroll
        for (int i = 0; i < (BN * BK) / (256 * 8); ++i) {
            int idx = i * 256 + t;
            int row = idx >> 2;
            int kof = (idx & 3) << 3;
            gl2lds16(BT + (size_t)(n0 + row) * K + kt + kof, &lB[idx * 8]);
        }
        __syncthreads();

        bf16x8 af[R], bfr[C];
#pragma unroll
        for (int r = 0; r < R; ++r)
            af[r] = *(const bf16x8*)&lA[(wr * R * 16 + r * 16 + lm) * BK + quad * 8];
#pragma unroll
        for (int c = 0; c < C; ++c)
            bfr[c] = *(const bf16x8*)&lB[(wc * C * 16 + c * 16 + lm) * BK + quad * 8];
#pragma unroll
        for (int r = 0; r < R; ++r)
#pragma unroll
            for (int c = 0; c < C; ++c)
                acc[r][c] = __builtin_amdgcn_mfma_f32_16x16x32_bf16(af[r], bfr[c],
                                                                    acc[r][c], 0, 0, 0);
        __syncthreads();
    }

#pragma unroll
    for (int r = 0; r < R; ++r) {
#pragma unroll
        for (int c = 0; c < C; ++c) {
            const int colg = n0 + wc * C * 16 + c * 16 + lm;
            const float bb = HASBIAS ? bias[colg] : 0.0f;
            const int rowb = m0 + wr * R * 16 + r * 16 + quad * 4;
#pragma unroll
            for (int i = 0; i < 4; ++i) {
                const int rr = rowb + i;
                if (rr < M) {
                    float v = acc[r][c][i] + bb;
                    if (RELU) v = fmaxf(v, 0.0f);
                    if (OUTBF16)
                        ((unsigned short*)Cout)[(size_t)rr * N + colg] = f2bf(v);
                    else
                        ((float*)Cout)[(size_t)rr * N + colg] = v;
                }
            }
        }
    }
}

// ================= CSR-pull aggregation =================
// one wave per dst node (4 nodes per block); lane owns 8 features (16B loads).
__global__ __launch_bounds__(256) void gcn_aggregate(const unsigned short* __restrict__ hW,
                                                     const int* __restrict__ row_ptr,
                                                     const int* __restrict__ col,
                                                     const float* __restrict__ wgt,
                                                     const float* __restrict__ dinv,
                                                     const float* __restrict__ bias,
                                                     unsigned short* __restrict__ out) {
    const int wv   = threadIdx.x >> 6;
    const int lane = threadIdx.x & 63;
    const int d    = blockIdx.x * 4 + wv;
    if (d >= N_NODES) return;
    const int beg = row_ptr[d];
    const int end = row_ptr[d + 1];
    const size_t foff = (size_t)lane * 8;

    const float di = dinv[d];
    const float sl = di * di;
    u16x8 sv = *(const u16x8*)(hW + (size_t)d * NHID + foff);
    float acc[8];
#pragma unroll
    for (int i = 0; i < 8; ++i) acc[i] = bf2f(sv[i]) * sl;

    for (int j = beg; j < end; ++j) {
        const int s   = col[j];
        const float w = wgt[j];
        u16x8 v = *(const u16x8*)(hW + (size_t)s * NHID + foff);
#pragma unroll
        for (int i = 0; i < 8; ++i) acc[i] += bf2f(v[i]) * w;
    }

    const float4 b0 = *(const float4*)(bias + foff);
    const float4 b1 = *(const float4*)(bias + foff + 4);
    u16x8 r;
    r[0] = f2bf(fmaxf(acc[0] + b0.x, 0.0f));
    r[1] = f2bf(fmaxf(acc[1] + b0.y, 0.0f));
    r[2] = f2bf(fmaxf(acc[2] + b0.z, 0.0f));
    r[3] = f2bf(fmaxf(acc[3] + b0.w, 0.0f));
    r[4] = f2bf(fmaxf(acc[4] + b1.x, 0.0f));
    r[5] = f2bf(fmaxf(acc[5] + b1.y, 0.0f));
    r[6] = f2bf(fmaxf(acc[6] + b1.z, 0.0f));
    r[7] = f2bf(fmaxf(acc[7] + b1.w, 0.0f));
    *(u16x8*)(out + (size_t)d * NHID + foff) = r;
}

// ================= launch =================
extern "C" void kernel_launch(void* const* d_in, const int* in_sizes, int n_in,
                              void* d_out, int out_size, void* d_ws, size_t ws_size,
                              hipStream_t stream) {
    const float* x       = (const float*)d_in[0];
    const int*   ei      = (const int*)d_in[1];
    const float* W_enc   = (const float*)d_in[2];
    const float* b_enc   = (const float*)d_in[3];
    const float* W_convs = (const float*)d_in[4];
    const float* b_convs = (const float*)d_in[5];
    const float* W_dec   = (const float*)d_in[6];
    const float* b_dec   = (const float*)d_in[7];
    float* out = (float*)d_out;

    const int* src = ei;
    const int* dst = ei + E_EDGES;

    char* ws = (char*)d_ws;
    auto alloc = [&](size_t bytes) {
        char* p = ws;
        ws += (bytes + 255) / 256 * 256;
        return p;
    };
    float* dinv     = (float*)alloc(N_NODES * 4);
    int*   counts   = (int*)  alloc(N_NODES * 4);
    int*   row_ptr  = (int*)  alloc((N_NODES + 1) * 4);
    int*   cursor   = (int*)  alloc(N_NODES * 4);
    int*   bsums    = (int*)  alloc(NBLK * 4);
    int*   boffs    = (int*)  alloc(NBLK * 4);
    int*   colA     = (int*)  alloc(E_EDGES * 4);
    float* wgtA     = (float*)alloc(E_EDGES * 4);
    unsigned short* xbf   = (unsigned short*)alloc((size_t)N_NODES * NFEAT * 2);
    unsigned short* WencT = (unsigned short*)alloc((size_t)NFEAT * NHID * 2);
    unsigned short* WcvT  = (unsigned short*)alloc((size_t)NLAYERS * NHID * NHID * 2);
    unsigned short* WdecT = (unsigned short*)alloc((size_t)NHID * NCLASS * 2);
    unsigned short* B1    = (unsigned short*)alloc((size_t)N_NODES * NHID * 2);
    unsigned short* B2    = (unsigned short*)alloc((size_t)N_NODES * NHID * 2);

    // ---- CSR build ----
    hipMemsetAsync(counts, 0, N_NODES * sizeof(int), stream);
    csr_count<<<(E_EDGES + 255) / 256, 256, 0, stream>>>(dst, counts);
    block_sums<<<NBLK, 256, 0, stream>>>(counts, bsums);
    scan_bsums<<<1, 64, 0, stream>>>(bsums, boffs);
    write_rowptr<<<NBLK, 256, 0, stream>>>(counts, boffs, row_ptr);
    node_prep<<<(N_NODES + 255) / 256, 256, 0, stream>>>(counts, row_ptr, dinv, cursor);
    csr_fill<<<(E_EDGES + 255) / 256, 256, 0, stream>>>(src, dst, dinv, cursor, colA, wgtA);

    // ---- convert inputs to bf16 ----
    {
        int n4 = N_NODES * NFEAT / 4;
        conv_f32_bf16<<<(n4 + 255) / 256, 256, 0, stream>>>(x, xbf, n4);
    }
    transpose_bf16<<<dim3(NHID / 32, NFEAT / 32), 256, 0, stream>>>(W_enc, WencT, NFEAT, NHID);
    for (int L = 0; L < NLAYERS; ++L)
        transpose_bf16<<<dim3(NHID / 32, NHID / 32), 256, 0, stream>>>(
            W_convs + (size_t)L * NHID * NHID, WcvT + (size_t)L * NHID * NHID, NHID, NHID);
    transpose_bf16<<<dim3(NCLASS / 32, NHID / 32), 256, 0, stream>>>(W_dec, WdecT, NHID, NCLASS);

    const int MB = (N_NODES + 127) / 128;   // 157

    // ---- encoder ----
    gemm_mfma<128, true, true, true><<<dim3(NHID / 128, MB), 256, 0, stream>>>(
        xbf, WencT, b_enc, B1, N_NODES, NHID, NFEAT);

    // ---- conv layers ----
    for (int L = 0; L < NLAYERS; ++L) {
        gemm_mfma<128, false, false, true><<<dim3(NHID / 128, MB), 256, 0, stream>>>(
            B1, WcvT + (size_t)L * NHID * NHID, nullptr, B2, N_NODES, NHID, NHID);
        gcn_aggregate<<<(N_NODES + 3) / 4, 256, 0, stream>>>(
            B2, row_ptr, colA, wgtA, dinv, b_convs + (size_t)L * NHID, B1);
    }

    // ---- decoder ----
    gemm_mfma<64, false, true, false><<<dim3(NCLASS / 64, MB), 256, 0, stream>>>(
        B1, WdecT, b_dec, out, N_NODES, NCLASS, NHID);
}

// Round 5
// 378.031 us; speedup vs baseline: 14.5495x; 1.0580x over previous
//
#include <hip/hip_runtime.h>

#define N_NODES 20000
#define E_EDGES 160000
#define NFEAT   512
#define NHID    512
#define NCLASS  64
#define NLAYERS 4

#define SCAN_CHUNK 1024
#define NBLK ((N_NODES + SCAN_CHUNK - 1) / SCAN_CHUNK)   // 20

using bf16x8 = __attribute__((ext_vector_type(8))) short;          // MFMA A/B frag
using f32x4  = __attribute__((ext_vector_type(4))) float;          // MFMA C/D frag
using u16x8  = __attribute__((ext_vector_type(8))) unsigned short; // 16B bf16 vector

__device__ __forceinline__ unsigned short f2bf(float f) {
    union { float f; unsigned int u; } v; v.f = f;
    unsigned int u = v.u + 0x7FFFu + ((v.u >> 16) & 1u);   // RNE
    return (unsigned short)(u >> 16);
}
__device__ __forceinline__ float bf2f(unsigned short h) {
    union { unsigned int u; float f; } v; v.u = ((unsigned int)h) << 16;
    return v.f;
}
__device__ __forceinline__ void gl2lds16(const void* gptr, void* lptr) {
    __builtin_amdgcn_global_load_lds(
        (const __attribute__((address_space(1))) unsigned int*)gptr,
        (__attribute__((address_space(3))) unsigned int*)lptr,
        16, 0, 0);
}

// ================= preprocessing =================

__global__ __launch_bounds__(256) void conv_f32_bf16(const float* __restrict__ in,
                                                     unsigned short* __restrict__ out,
                                                     int n4) {
    int i = blockIdx.x * 256 + threadIdx.x;
    if (i < n4) {
        float4 v = ((const float4*)in)[i];
        ushort4 o;
        o.x = f2bf(v.x); o.y = f2bf(v.y); o.z = f2bf(v.z); o.w = f2bf(v.w);
        ((ushort4*)out)[i] = o;
    }
}

// one kernel transposes+converts all 6 weight matrices; blockIdx.z = matrix id
__global__ __launch_bounds__(256) void transpose_all(const float* __restrict__ W_enc,
                                                     const float* __restrict__ W_convs,
                                                     const float* __restrict__ W_dec,
                                                     unsigned short* __restrict__ WencT,
                                                     unsigned short* __restrict__ WcvT,
                                                     unsigned short* __restrict__ WdecT) {
    __shared__ float tile[32][33];
    const int id = blockIdx.z;
    const float* W; unsigned short* WT; int N;
    const int K = 512;                    // all matrices have K=512
    if (id == 0)                { W = W_enc; WT = WencT; N = NHID; }
    else if (id <= NLAYERS)     { W = W_convs + (size_t)(id - 1) * NHID * NHID;
                                  WT = WcvT  + (size_t)(id - 1) * NHID * NHID; N = NHID; }
    else                        { W = W_dec; WT = WdecT; N = NCLASS; }

    const int n0 = blockIdx.x * 32;
    if (n0 >= N) return;                  // decoder uses only 2 of 16 x-blocks
    const int k0 = blockIdx.y * 32;
    const int tx = threadIdx.x & 31, ty = threadIdx.x >> 5;
#pragma unroll
    for (int i = 0; i < 32; i += 8)
        tile[ty + i][tx] = W[(size_t)(k0 + ty + i) * N + n0 + tx];
    __syncthreads();
#pragma unroll
    for (int i = 0; i < 32; i += 8)
        WT[(size_t)(n0 + ty + i) * K + k0 + tx] = f2bf(tile[tx][ty + i]);
}

// ================= CSR build =================
__global__ __launch_bounds__(256) void csr_count(const int* __restrict__ dst,
                                                 int* __restrict__ counts) {
    int e = blockIdx.x * 256 + threadIdx.x;
    if (e < E_EDGES) atomicAdd(&counts[dst[e]], 1);
}

__global__ __launch_bounds__(256) void block_sums(const int* __restrict__ counts,
                                                  int* __restrict__ bsums) {
    __shared__ int red[256];
    const int b = blockIdx.x, t = threadIdx.x;
    const int base = b * SCAN_CHUNK + t * 4;
    int s = 0;
    if (base + 3 < N_NODES) {
        int4 v = *(const int4*)(counts + base);
        s = v.x + v.y + v.z + v.w;
    } else {
        for (int i = 0; i < 4; ++i)
            if (base + i < N_NODES) s += counts[base + i];
    }
    red[t] = s;
    __syncthreads();
    for (int off = 128; off > 0; off >>= 1) {
        if (t < off) red[t] += red[t + off];
        __syncthreads();
    }
    if (t == 0) bsums[b] = red[0];
}

__global__ __launch_bounds__(64) void scan_bsums(const int* __restrict__ bsums,
                                                 int* __restrict__ boffs) {
    const int t = threadIdx.x;
    const int orig = (t < NBLK) ? bsums[t] : 0;
    int v = orig;
    for (int off = 1; off < 64; off <<= 1) {
        int u = __shfl_up(v, off, 64);
        if (t >= off) v += u;
    }
    if (t < NBLK) boffs[t] = v - orig;   // exclusive
}

// phase 3 + node_prep fused: row_ptr, cursor, dinv in one pass
__global__ __launch_bounds__(256) void write_rowptr(const int* __restrict__ counts,
                                                    const int* __restrict__ boffs,
                                                    int* __restrict__ row_ptr,
                                                    int* __restrict__ cursor,
                                                    float* __restrict__ dinv) {
    __shared__ int part[256];
    const int b = blockIdx.x, t = threadIdx.x;
    const int base = b * SCAN_CHUNK + t * 4;
    int c[4], s = 0;
    for (int i = 0; i < 4; ++i) {
        int idx = base + i;
        c[i] = (idx < N_NODES) ? counts[idx] : 0;
        s += c[i];
    }
    part[t] = s;
    __syncthreads();
    for (int off = 1; off < 256; off <<= 1) {
        int v = (t >= off) ? part[t - off] : 0;
        __syncthreads();
        part[t] += v;
        __syncthreads();
    }
    int run = boffs[b] + ((t == 0) ? 0 : part[t - 1]);
    for (int i = 0; i < 4; ++i) {
        int idx = base + i;
        if (idx < N_NODES) {
            row_ptr[idx] = run;
            cursor[idx]  = run;
            dinv[idx]    = rsqrtf((float)c[i] + 1.0f);
            run += c[i];
        }
    }
    if (b == 0 && t == 0) row_ptr[N_NODES] = E_EDGES;
}

__global__ __launch_bounds__(256) void csr_fill(const int* __restrict__ src,
                                                const int* __restrict__ dst,
                                                const float* __restrict__ dinv,
                                                int* __restrict__ cursor,
                                                int* __restrict__ col,
                                                float* __restrict__ wgt) {
    int e = blockIdx.x * 256 + threadIdx.x;
    if (e < E_EDGES) {
        int s = src[e], d = dst[e];
        int pos = atomicAdd(&cursor[d], 1);
        col[pos] = s;
        wgt[pos] = dinv[s] * dinv[d];
    }
}

// ================= bf16 MFMA GEMM =================
template <int BN, bool RELU, bool HASBIAS, bool OUTBF16>
__global__ __launch_bounds__(256) void gemm_mfma(const unsigned short* __restrict__ A,
                                                 const unsigned short* __restrict__ BT,
                                                 const float* __restrict__ bias,
                                                 void* __restrict__ Cout,
                                                 int M, int N, int K) {
    constexpr int BM = 128, BK = 32;
    constexpr int R = (BN == 128) ? 4 : 2;
    constexpr int C = 4;
    __shared__ unsigned short lA[BM * BK];
    __shared__ unsigned short lB[BN * BK];

    const int t    = threadIdx.x;
    const int lane = t & 63;
    const int wv   = t >> 6;
    const int wr   = (BN == 128) ? (wv >> 1) : wv;
    const int wc   = (BN == 128) ? (wv & 1) : 0;
    const int lm   = lane & 15;
    const int quad = lane >> 4;

    const int m0 = blockIdx.y * BM;
    const int n0 = blockIdx.x * BN;

    f32x4 acc[R][C] = {};

    for (int kt = 0; kt < K; kt += BK) {
#pragma unroll
        for (int i = 0; i < (BM * BK) / (256 * 8); ++i) {
            int idx = i * 256 + t;
            int row = idx >> 2;
            int kof = (idx & 3) << 3;
            int gr = m0 + row; if (gr >= M) gr = M - 1;
            gl2lds16(A + (size_t)gr * K + kt + kof, &lA[idx * 8]);
        }
#pragma unroll
        for (int i = 0; i < (BN * BK) / (256 * 8); ++i) {
            int idx = i * 256 + t;
            int row = idx >> 2;
            int kof = (idx & 3) << 3;
            gl2lds16(BT + (size_t)(n0 + row) * K + kt + kof, &lB[idx * 8]);
        }
        __syncthreads();

        bf16x8 af[R], bfr[C];
#pragma unroll
        for (int r = 0; r < R; ++r)
            af[r] = *(const bf16x8*)&lA[(wr * R * 16 + r * 16 + lm) * BK + quad * 8];
#pragma unroll
        for (int c = 0; c < C; ++c)
            bfr[c] = *(const bf16x8*)&lB[(wc * C * 16 + c * 16 + lm) * BK + quad * 8];
#pragma unroll
        for (int r = 0; r < R; ++r)
#pragma unroll
            for (int c = 0; c < C; ++c)
                acc[r][c] = __builtin_amdgcn_mfma_f32_16x16x32_bf16(af[r], bfr[c],
                                                                    acc[r][c], 0, 0, 0);
        __syncthreads();
    }

#pragma unroll
    for (int r = 0; r < R; ++r) {
#pragma unroll
        for (int c = 0; c < C; ++c) {
            const int colg = n0 + wc * C * 16 + c * 16 + lm;
            const float bb = HASBIAS ? bias[colg] : 0.0f;
            const int rowb = m0 + wr * R * 16 + r * 16 + quad * 4;
#pragma unroll
            for (int i = 0; i < 4; ++i) {
                const int rr = rowb + i;
                if (rr < M) {
                    float v = acc[r][c][i] + bb;
                    if (RELU) v = fmaxf(v, 0.0f);
                    if (OUTBF16)
                        ((unsigned short*)Cout)[(size_t)rr * N + colg] = f2bf(v);
                    else
                        ((float*)Cout)[(size_t)rr * N + colg] = v;
                }
            }
        }
    }
}

// ================= CSR-pull aggregation, ILP gather =================
// one wave per dst node; lane owns 8 features. Bulk-load up to 64 col/wgt into
// lanes, shfl-broadcast, then issue 8 INDEPENDENT row loads per group so the
// LLC latency overlaps (was: serial col->row chain, ~700cyc/edge).
__global__ __launch_bounds__(256) void gcn_aggregate(const unsigned short* __restrict__ hW,
                                                     const int* __restrict__ row_ptr,
                                                     const int* __restrict__ col,
                                                     const float* __restrict__ wgt,
                                                     const float* __restrict__ dinv,
                                                     const float* __restrict__ bias,
                                                     unsigned short* __restrict__ out) {
    const int wv   = threadIdx.x >> 6;
    const int lane = threadIdx.x & 63;
    const int d    = blockIdx.x * 4 + wv;
    if (d >= N_NODES) return;
    const int beg = row_ptr[d];
    const int end = row_ptr[d + 1];
    const size_t foff = (size_t)lane * 8;

    const float di = dinv[d];
    const float sl = di * di;
    u16x8 sv = *(const u16x8*)(hW + (size_t)d * NHID + foff);
    float acc[8];
#pragma unroll
    for (int i = 0; i < 8; ++i) acc[i] = bf2f(sv[i]) * sl;

    for (int b0 = beg; b0 < end; b0 += 64) {
        const int nb   = min(64, end - b0);
        const int last = nb - 1;
        int   myc = 0;
        float myw = 0.0f;
        if (lane < nb) { myc = col[b0 + lane]; myw = wgt[b0 + lane]; }

        for (int j = 0; j < nb; j += 8) {
            // broadcast 8 (col,wgt) pairs; clamp index for safe loads, zero wgt OOB
            int   s[8];
            float w[8];
            u16x8 v[8];
#pragma unroll
            for (int k = 0; k < 8; ++k) {
                const int jj = j + k;
                s[k] = __shfl(myc, jj <= last ? jj : last);
                w[k] = (jj <= last) ? __shfl(myw, jj) : 0.0f;
            }
            // 8 independent 16B loads -> all in flight before first use
#pragma unroll
            for (int k = 0; k < 8; ++k)
                v[k] = *(const u16x8*)(hW + (size_t)s[k] * NHID + foff);
#pragma unroll
            for (int k = 0; k < 8; ++k)
#pragma unroll
                for (int i = 0; i < 8; ++i)
                    acc[i] += bf2f(v[k][i]) * w[k];
        }
    }

    const float4 b0v = *(const float4*)(bias + foff);
    const float4 b1v = *(const float4*)(bias + foff + 4);
    u16x8 r;
    r[0] = f2bf(fmaxf(acc[0] + b0v.x, 0.0f));
    r[1] = f2bf(fmaxf(acc[1] + b0v.y, 0.0f));
    r[2] = f2bf(fmaxf(acc[2] + b0v.z, 0.0f));
    r[3] = f2bf(fmaxf(acc[3] + b0v.w, 0.0f));
    r[4] = f2bf(fmaxf(acc[4] + b1v.x, 0.0f));
    r[5] = f2bf(fmaxf(acc[5] + b1v.y, 0.0f));
    r[6] = f2bf(fmaxf(acc[6] + b1v.z, 0.0f));
    r[7] = f2bf(fmaxf(acc[7] + b1v.w, 0.0f));
    *(u16x8*)(out + (size_t)d * NHID + foff) = r;
}

// ================= launch =================
extern "C" void kernel_launch(void* const* d_in, const int* in_sizes, int n_in,
                              void* d_out, int out_size, void* d_ws, size_t ws_size,
                              hipStream_t stream) {
    const float* x       = (const float*)d_in[0];
    const int*   ei      = (const int*)d_in[1];
    const float* W_enc   = (const float*)d_in[2];
    const float* b_enc   = (const float*)d_in[3];
    const float* W_convs = (const float*)d_in[4];
    const float* b_convs = (const float*)d_in[5];
    const float* W_dec   = (const float*)d_in[6];
    const float* b_dec   = (const float*)d_in[7];
    float* out = (float*)d_out;

    const int* src = ei;
    const int* dst = ei + E_EDGES;

    char* ws = (char*)d_ws;
    auto alloc = [&](size_t bytes) {
        char* p = ws;
        ws += (bytes + 255) / 256 * 256;
        return p;
    };
    float* dinv     = (float*)alloc(N_NODES * 4);
    int*   counts   = (int*)  alloc(N_NODES * 4);
    int*   row_ptr  = (int*)  alloc((N_NODES + 1) * 4);
    int*   cursor   = (int*)  alloc(N_NODES * 4);
    int*   bsums    = (int*)  alloc(NBLK * 4);
    int*   boffs    = (int*)  alloc(NBLK * 4);
    int*   colA     = (int*)  alloc(E_EDGES * 4);
    float* wgtA     = (float*)alloc(E_EDGES * 4);
    unsigned short* xbf   = (unsigned short*)alloc((size_t)N_NODES * NFEAT * 2);
    unsigned short* WencT = (unsigned short*)alloc((size_t)NFEAT * NHID * 2);
    unsigned short* WcvT  = (unsigned short*)alloc((size_t)NLAYERS * NHID * NHID * 2);
    unsigned short* WdecT = (unsigned short*)alloc((size_t)NHID * NCLASS * 2);
    unsigned short* B1    = (unsigned short*)alloc((size_t)N_NODES * NHID * 2);
    unsigned short* B2    = (unsigned short*)alloc((size_t)N_NODES * NHID * 2);

    // ---- CSR build ----
    hipMemsetAsync(counts, 0, N_NODES * sizeof(int), stream);
    csr_count<<<(E_EDGES + 255) / 256, 256, 0, stream>>>(dst, counts);
    block_sums<<<NBLK, 256, 0, stream>>>(counts, bsums);
    scan_bsums<<<1, 64, 0, stream>>>(bsums, boffs);
    write_rowptr<<<NBLK, 256, 0, stream>>>(counts, boffs, row_ptr, cursor, dinv);
    csr_fill<<<(E_EDGES + 255) / 256, 256, 0, stream>>>(src, dst, dinv, cursor, colA, wgtA);

    // ---- convert inputs to bf16 ----
    {
        int n4 = N_NODES * NFEAT / 4;
        conv_f32_bf16<<<(n4 + 255) / 256, 256, 0, stream>>>(x, xbf, n4);
    }
    transpose_all<<<dim3(16, 16, NLAYERS + 2), 256, 0, stream>>>(
        W_enc, W_convs, W_dec, WencT, WcvT, WdecT);

    const int MB = (N_NODES + 127) / 128;   // 157

    // ---- encoder ----
    gemm_mfma<128, true, true, true><<<dim3(NHID / 128, MB), 256, 0, stream>>>(
        xbf, WencT, b_enc, B1, N_NODES, NHID, NFEAT);

    // ---- conv layers ----
    for (int L = 0; L < NLAYERS; ++L) {
        gemm_mfma<128, false, false, true><<<dim3(NHID / 128, MB), 256, 0, stream>>>(
            B1, WcvT + (size_t)L * NHID * NHID, nullptr, B2, N_NODES, NHID, NHID);
        gcn_aggregate<<<(N_NODES + 3) / 4, 256, 0, stream>>>(
            B2, row_ptr, colA, wgtA, dinv, b_convs + (size_t)L * NHID, B1);
    }

    // ---- decoder ----
    gemm_mfma<64, false, true, false><<<dim3(NCLASS / 64, MB), 256, 0, stream>>>(
        B1, WdecT, b_dec, out, N_NODES, NCLASS, NHID);
}

// Round 6
// 363.166 us; speedup vs baseline: 15.1450x; 1.0409x over previous
//
#include <hip/hip_runtime.h>

#define N_NODES 20000
#define E_EDGES 160000
#define NFEAT   512
#define NHID    512
#define NCLASS  64
#define NLAYERS 4

#define SCAN_CHUNK 1024
#define NBLK ((N_NODES + SCAN_CHUNK - 1) / SCAN_CHUNK)   // 20
#define CNT_BLOCKS ((E_EDGES + 255) / 256)               // 625

using bf16x8 = __attribute__((ext_vector_type(8))) short;          // MFMA A/B frag
using f32x4  = __attribute__((ext_vector_type(4))) float;          // MFMA C/D frag
using u16x8  = __attribute__((ext_vector_type(8))) unsigned short; // 16B bf16 vector

__device__ __forceinline__ unsigned short f2bf(float f) {
    union { float f; unsigned int u; } v; v.f = f;
    unsigned int u = v.u + 0x7FFFu + ((v.u >> 16) & 1u);   // RNE
    return (unsigned short)(u >> 16);
}
__device__ __forceinline__ float bf2f(unsigned short h) {
    union { unsigned int u; float f; } v; v.u = ((unsigned int)h) << 16;
    return v.f;
}
__device__ __forceinline__ void gl2lds16(const void* gptr, void* lptr) {
    __builtin_amdgcn_global_load_lds(
        (const __attribute__((address_space(1))) unsigned int*)gptr,
        (__attribute__((address_space(3))) unsigned int*)lptr,
        16, 0, 0);
}

// ================= fused prep: edge counting + chunk bins + weight transposes ==
// blocks [0, CNT_BLOCKS): count in-degree, accumulate per-1024-chunk bins
// blocks [CNT_BLOCKS, CNT_BLOCKS + 6*256): transpose+convert the 6 weights
__global__ __launch_bounds__(256) void prep_all(const int* __restrict__ dst,
                                                int* __restrict__ counts,
                                                int* __restrict__ bsums,
                                                const float* __restrict__ W_enc,
                                                const float* __restrict__ W_convs,
                                                const float* __restrict__ W_dec,
                                                unsigned short* __restrict__ WencT,
                                                unsigned short* __restrict__ WcvT,
                                                unsigned short* __restrict__ WdecT) {
    __shared__ int bins[NBLK];
    __shared__ float tile[32][33];
    const int b = blockIdx.x, t = threadIdx.x;

    if (b < CNT_BLOCKS) {
        if (t < NBLK) bins[t] = 0;
        __syncthreads();
        const int e = b * 256 + t;
        if (e < E_EDGES) {
            const int d = dst[e];
            atomicAdd(&counts[d], 1);
            atomicAdd(&bins[d >> 10], 1);         // SCAN_CHUNK = 1024
        }
        __syncthreads();
        if (t < NBLK && bins[t]) atomicAdd(&bsums[t], bins[t]);
        return;
    }

    // ---- transpose role ----
    const int bid = b - CNT_BLOCKS;
    const int id  = bid >> 8;            // matrix 0..5
    const int rem = bid & 255;
    const int n0  = (rem & 15) * 32;
    const int k0  = (rem >> 4) * 32;
    const float* W; unsigned short* WT; int N;
    const int K = 512;
    if (id == 0)            { W = W_enc; WT = WencT; N = NHID; }
    else if (id <= NLAYERS) { W = W_convs + (size_t)(id - 1) * NHID * NHID;
                              WT = WcvT  + (size_t)(id - 1) * NHID * NHID; N = NHID; }
    else                    { W = W_dec; WT = WdecT; N = NCLASS; }
    if (n0 >= N) return;
    const int tx = t & 31, ty = t >> 5;
#pragma unroll
    for (int i = 0; i < 32; i += 8)
        tile[ty + i][tx] = W[(size_t)(k0 + ty + i) * N + n0 + tx];
    __syncthreads();
#pragma unroll
    for (int i = 0; i < 32; i += 8)
        WT[(size_t)(n0 + ty + i) * K + k0 + tx] = f2bf(tile[tx][ty + i]);
}

// ================= scan =================
__global__ __launch_bounds__(64) void scan_bsums(const int* __restrict__ bsums,
                                                 int* __restrict__ boffs) {
    const int t = threadIdx.x;
    const int orig = (t < NBLK) ? bsums[t] : 0;
    int v = orig;
    for (int off = 1; off < 64; off <<= 1) {
        int u = __shfl_up(v, off, 64);
        if (t >= off) v += u;
    }
    if (t < NBLK) boffs[t] = v - orig;   // exclusive
}

// row_ptr + cursor + dinv in one pass
__global__ __launch_bounds__(256) void write_rowptr(const int* __restrict__ counts,
                                                    const int* __restrict__ boffs,
                                                    int* __restrict__ row_ptr,
                                                    int* __restrict__ cursor,
                                                    float* __restrict__ dinv) {
    __shared__ int part[256];
    const int b = blockIdx.x, t = threadIdx.x;
    const int base = b * SCAN_CHUNK + t * 4;
    int c[4], s = 0;
    for (int i = 0; i < 4; ++i) {
        int idx = base + i;
        c[i] = (idx < N_NODES) ? counts[idx] : 0;
        s += c[i];
    }
    part[t] = s;
    __syncthreads();
    for (int off = 1; off < 256; off <<= 1) {
        int v = (t >= off) ? part[t - off] : 0;
        __syncthreads();
        part[t] += v;
        __syncthreads();
    }
    int run = boffs[b] + ((t == 0) ? 0 : part[t - 1]);
    for (int i = 0; i < 4; ++i) {
        int idx = base + i;
        if (idx < N_NODES) {
            row_ptr[idx] = run;
            cursor[idx]  = run;
            dinv[idx]    = rsqrtf((float)c[i] + 1.0f);
            run += c[i];
        }
    }
    if (b == 0 && t == 0) row_ptr[N_NODES] = E_EDGES;
}

// fill packed (col, wgt) pairs; pad 8 entries past E with {node 0, weight 0}
__global__ __launch_bounds__(256) void csr_fill(const int* __restrict__ src,
                                                const int* __restrict__ dst,
                                                const float* __restrict__ dinv,
                                                int* __restrict__ cursor,
                                                int2* __restrict__ ew) {
    int e = blockIdx.x * 256 + threadIdx.x;
    if (e < E_EDGES) {
        int s = src[e], d = dst[e];
        int pos = atomicAdd(&cursor[d], 1);
        ew[pos] = make_int2(s, __float_as_int(dinv[s] * dinv[d]));
    }
    if (e < 8) ew[E_EDGES + e] = make_int2(0, 0);
}

// ================= bf16 MFMA GEMM =================
// C[M,N] = A[M,K] @ B[K,N]; BT = B^T bf16 [N][K]. A is bf16 (global_load_lds)
// or fp32 (A32=true: load->convert->ds_write, used by the encoder).
template <int BN, bool RELU, bool HASBIAS, bool OUTBF16, bool A32>
__global__ __launch_bounds__(256) void gemm_mfma(const void* __restrict__ Aptr,
                                                 const unsigned short* __restrict__ BT,
                                                 const float* __restrict__ bias,
                                                 void* __restrict__ Cout,
                                                 int M, int N, int K) {
    constexpr int BM = 128, BK = 32;
    constexpr int R = (BN == 128) ? 4 : 2;
    constexpr int C = 4;
    __shared__ unsigned short lA[BM * BK];
    __shared__ unsigned short lB[BN * BK];

    const int t    = threadIdx.x;
    const int lane = t & 63;
    const int wv   = t >> 6;
    const int wr   = (BN == 128) ? (wv >> 1) : wv;
    const int wc   = (BN == 128) ? (wv & 1) : 0;
    const int lm   = lane & 15;
    const int quad = lane >> 4;

    const int m0 = blockIdx.y * BM;
    const int n0 = blockIdx.x * BN;

    f32x4 acc[R][C] = {};

    for (int kt = 0; kt < K; kt += BK) {
        // ---- stage A tile ----
#pragma unroll
        for (int i = 0; i < (BM * BK) / (256 * 8); ++i) {
            int idx = i * 256 + t;
            int row = idx >> 2;
            int kof = (idx & 3) << 3;
            int gr = m0 + row; if (gr >= M) gr = M - 1;
            if constexpr (!A32) {
                gl2lds16((const unsigned short*)Aptr + (size_t)gr * K + kt + kof,
                         &lA[idx * 8]);
            } else {
                const float* p = (const float*)Aptr + (size_t)gr * K + kt + kof;
                float4 f0 = *(const float4*)p;
                float4 f1 = *(const float4*)(p + 4);
                u16x8 pk;
                pk[0] = f2bf(f0.x); pk[1] = f2bf(f0.y);
                pk[2] = f2bf(f0.z); pk[3] = f2bf(f0.w);
                pk[4] = f2bf(f1.x); pk[5] = f2bf(f1.y);
                pk[6] = f2bf(f1.z); pk[7] = f2bf(f1.w);
                *(u16x8*)&lA[idx * 8] = pk;
            }
        }
        // ---- stage B^T tile ----
#pragma unroll
        for (int i = 0; i < (BN * BK) / (256 * 8); ++i) {
            int idx = i * 256 + t;
            int row = idx >> 2;
            int kof = (idx & 3) << 3;
            gl2lds16(BT + (size_t)(n0 + row) * K + kt + kof, &lB[idx * 8]);
        }
        __syncthreads();

        bf16x8 af[R], bfr[C];
#pragma unroll
        for (int r = 0; r < R; ++r)
            af[r] = *(const bf16x8*)&lA[(wr * R * 16 + r * 16 + lm) * BK + quad * 8];
#pragma unroll
        for (int c = 0; c < C; ++c)
            bfr[c] = *(const bf16x8*)&lB[(wc * C * 16 + c * 16 + lm) * BK + quad * 8];
#pragma unroll
        for (int r = 0; r < R; ++r)
#pragma unroll
            for (int c = 0; c < C; ++c)
                acc[r][c] = __builtin_amdgcn_mfma_f32_16x16x32_bf16(af[r], bfr[c],
                                                                    acc[r][c], 0, 0, 0);
        __syncthreads();
    }

#pragma unroll
    for (int r = 0; r < R; ++r) {
#pragma unroll
        for (int c = 0; c < C; ++c) {
            const int colg = n0 + wc * C * 16 + c * 16 + lm;
            const float bb = HASBIAS ? bias[colg] : 0.0f;
            const int rowb = m0 + wr * R * 16 + r * 16 + quad * 4;
#pragma unroll
            for (int i = 0; i < 4; ++i) {
                const int rr = rowb + i;
                if (rr < M) {
                    float v = acc[r][c][i] + bb;
                    if (RELU) v = fmaxf(v, 0.0f);
                    if (OUTBF16)
                        ((unsigned short*)Cout)[(size_t)rr * N + colg] = f2bf(v);
                    else
                        ((float*)Cout)[(size_t)rr * N + colg] = v;
                }
            }
        }
    }
}

// ================= CSR-pull aggregation =================
// one wave per dst node; lane owns 8 features (16B). beg/end/col/wgt are
// wave-uniform -> scalar loads, no shuffles. Full 8-deep unconditional load
// groups; tail lanes redirect to row 0 with weight 0 (L1-hot, ~free).
__global__ __launch_bounds__(256) void gcn_aggregate(const unsigned short* __restrict__ hW,
                                                     const int* __restrict__ row_ptr,
                                                     const int2* __restrict__ ew,
                                                     const float* __restrict__ dinv,
                                                     const float* __restrict__ bias,
                                                     unsigned short* __restrict__ out) {
    const int wv   = threadIdx.x >> 6;
    const int lane = threadIdx.x & 63;
    int d = blockIdx.x * 4 + wv;
    d = __builtin_amdgcn_readfirstlane(d);
    if (d >= N_NODES) return;
    const int beg = __builtin_amdgcn_readfirstlane(row_ptr[d]);
    const int end = __builtin_amdgcn_readfirstlane(row_ptr[d + 1]);
    const size_t foff = (size_t)lane * 8;

    const float di = dinv[d];
    const float sl = di * di;
    u16x8 sv = *(const u16x8*)(hW + (size_t)d * NHID + foff);
    float acc[8];
#pragma unroll
    for (int i = 0; i < 8; ++i) acc[i] = bf2f(sv[i]) * sl;

    for (int j = beg; j < end; j += 8) {
        int   sK[8];
        float wK[8];
        u16x8 v[8];
#pragma unroll
        for (int k = 0; k < 8; ++k) {
            const int jj = j + k;            // may overrun into pad (safe)
            const int2 e = ew[jj];
            const bool valid = jj < end;     // wave-uniform
            sK[k] = valid ? e.x : 0;
            wK[k] = valid ? __int_as_float(e.y) : 0.0f;
        }
#pragma unroll
        for (int k = 0; k < 8; ++k)
            v[k] = *(const u16x8*)(hW + (size_t)sK[k] * NHID + foff);
#pragma unroll
        for (int k = 0; k < 8; ++k)
#pragma unroll
            for (int i = 0; i < 8; ++i)
                acc[i] += bf2f(v[k][i]) * wK[k];
    }

    const float4 b0v = *(const float4*)(bias + foff);
    const float4 b1v = *(const float4*)(bias + foff + 4);
    u16x8 r;
    r[0] = f2bf(fmaxf(acc[0] + b0v.x, 0.0f));
    r[1] = f2bf(fmaxf(acc[1] + b0v.y, 0.0f));
    r[2] = f2bf(fmaxf(acc[2] + b0v.z, 0.0f));
    r[3] = f2bf(fmaxf(acc[3] + b0v.w, 0.0f));
    r[4] = f2bf(fmaxf(acc[4] + b1v.x, 0.0f));
    r[5] = f2bf(fmaxf(acc[5] + b1v.y, 0.0f));
    r[6] = f2bf(fmaxf(acc[6] + b1v.z, 0.0f));
    r[7] = f2bf(fmaxf(acc[7] + b1v.w, 0.0f));
    *(u16x8*)(out + (size_t)d * NHID + foff) = r;
}

// ================= launch =================
extern "C" void kernel_launch(void* const* d_in, const int* in_sizes, int n_in,
                              void* d_out, int out_size, void* d_ws, size_t ws_size,
                              hipStream_t stream) {
    const float* x       = (const float*)d_in[0];
    const int*   ei      = (const int*)d_in[1];
    const float* W_enc   = (const float*)d_in[2];
    const float* b_enc   = (const float*)d_in[3];
    const float* W_convs = (const float*)d_in[4];
    const float* b_convs = (const float*)d_in[5];
    const float* W_dec   = (const float*)d_in[6];
    const float* b_dec   = (const float*)d_in[7];
    float* out = (float*)d_out;

    const int* src = ei;
    const int* dst = ei + E_EDGES;

    char* ws = (char*)d_ws;
    auto alloc = [&](size_t bytes) {
        char* p = ws;
        ws += (bytes + 255) / 256 * 256;
        return p;
    };
    float* dinv     = (float*)alloc(N_NODES * 4);
    int*   counts   = (int*)  alloc((N_NODES + NBLK) * 4);   // bsums adjacent
    int*   bsums    = counts + N_NODES;
    int*   row_ptr  = (int*)  alloc((N_NODES + 1) * 4);
    int*   cursor   = (int*)  alloc(N_NODES * 4);
    int*   boffs    = (int*)  alloc(NBLK * 4);
    int2*  ew       = (int2*) alloc((E_EDGES + 8) * 8);
    unsigned short* WencT = (unsigned short*)alloc((size_t)NFEAT * NHID * 2);
    unsigned short* WcvT  = (unsigned short*)alloc((size_t)NLAYERS * NHID * NHID * 2);
    unsigned short* WdecT = (unsigned short*)alloc((size_t)NHID * NCLASS * 2);
    unsigned short* B1    = (unsigned short*)alloc((size_t)N_NODES * NHID * 2);
    unsigned short* B2    = (unsigned short*)alloc((size_t)N_NODES * NHID * 2);

    // ---- CSR build + weight conversion (fused) ----
    hipMemsetAsync(counts, 0, (N_NODES + NBLK) * sizeof(int), stream);
    prep_all<<<CNT_BLOCKS + 6 * 256, 256, 0, stream>>>(
        dst, counts, bsums, W_enc, W_convs, W_dec, WencT, WcvT, WdecT);
    scan_bsums<<<1, 64, 0, stream>>>(bsums, boffs);
    write_rowptr<<<NBLK, 256, 0, stream>>>(counts, boffs, row_ptr, cursor, dinv);
    csr_fill<<<(E_EDGES + 255) / 256, 256, 0, stream>>>(src, dst, dinv, cursor, ew);

    const int MB = (N_NODES + 127) / 128;   // 157

    // ---- encoder (reads fp32 x, converts in staging) ----
    gemm_mfma<128, true, true, true, true><<<dim3(NHID / 128, MB), 256, 0, stream>>>(
        x, WencT, b_enc, B1, N_NODES, NHID, NFEAT);

    // ---- conv layers ----
    for (int L = 0; L < NLAYERS; ++L) {
        gemm_mfma<128, false, false, true, false><<<dim3(NHID / 128, MB), 256, 0, stream>>>(
            B1, WcvT + (size_t)L * NHID * NHID, nullptr, B2, N_NODES, NHID, NHID);
        gcn_aggregate<<<(N_NODES + 3) / 4, 256, 0, stream>>>(
            B2, row_ptr, ew, dinv, b_convs + (size_t)L * NHID, B1);
    }

    // ---- decoder ----
    gemm_mfma<64, false, true, false, false><<<dim3(NCLASS / 64, MB), 256, 0, stream>>>(
        B1, WdecT, b_dec, out, N_NODES, NCLASS, NHID);
}